// Round 3
// baseline (1276.551 us; speedup 1.0000x reference)
//
#include <hip/hip_runtime.h>
#include <hip/hip_cooperative_groups.h>

namespace cg = cooperative_groups;

#define NEG_SLOPE 0.2f

typedef __attribute__((ext_vector_type(8))) short bf16x8;
typedef __attribute__((ext_vector_type(4))) float f32x4;

__device__ __forceinline__ float leaky(float v) {
    return v > 0.0f ? v : NEG_SLOPE * v;
}
__device__ __forceinline__ float elu(float v) {
    return v > 0.0f ? v : (__expf(v) - 1.0f);
}
__device__ __forceinline__ short f2b(float f) {
    return (short)((__float_as_uint(f) + 0x8000u) >> 16);
}
__device__ __forceinline__ float bf2f(unsigned short v) {
    return __uint_as_float(((unsigned)v) << 16);
}

struct GP {
    const float* x; const int* ei;
    const float* W1; const float* as1; const float* ad1; const float* b1;
    const float* W2; const float* as2; const float* ad2; const float* b2;
    unsigned short* w1s; unsigned short* w2s;
    unsigned short* out1b; unsigned short* h1b; unsigned short* h2b;
    float* s1; float* d1; float* s2; float* d2;
    int* beg; int* deg; int* wp; int* srcs;   // deg has length N+1; deg[N] = ticket
    float* out;
    int N; int E;
};

// Phases [plo, phi] of the pipeline. Cooperative launch runs (0,6) with
// grid.sync() between phases; fallback runs 7 single-phase launches where
// kernel boundaries provide the device-wide barrier (grid.sync never called).
__global__ __launch_bounds__(256, 4) void fused_k(GP p, int plo, int phi) {
    cg::grid_group grid = cg::this_grid();
    const int tid  = threadIdx.x;
    const int bid  = blockIdx.x;
    const int nB   = gridDim.x;
    const int gsz  = nB * 256;
    const int gtid = bid * 256 + tid;
    const int lane = tid & 63;
    const int wave = tid >> 6;
    const int N = p.N, E = p.E;
    const int gblk = (N + 63) >> 6;
    const int nb   = (N + 1023) >> 10;
    const int nW   = gsz >> 6;
    const int gw   = gtid >> 6;

    __shared__ int sm[256];
    __shared__ int chunkBase;

    for (int ph = plo; ph <= phi; ++ph) {
        switch (ph) {
        case 0: {
            // ---------------- P0: weight swizzle + zero deg/ticket ----------------
            for (int i = gtid; i < 512 * 64 + 64 * 128; i += gsz) {
                if (i < 512 * 64) {                   // W1: K=512, Nc=64
                    int k = i >> 6, n = i & 63;
                    int kt = k >> 5, kk = k & 31;
                    int nt = n >> 4, nn = n & 15;
                    int l = (kk >> 3) * 16 + nn, j = kk & 7;
                    p.w1s[(((size_t)(kt * 4 + nt)) * 64 + l) * 8 + j] = (unsigned short)f2b(p.W1[i]);
                } else {                              // W2: K=64, Nc=128
                    int i2 = i - 512 * 64;
                    int k = i2 >> 7, n = i2 & 127;
                    int kt = k >> 5, kk = k & 31;
                    int nt = n >> 4, nn = n & 15;
                    int l = (kk >> 3) * 16 + nn, j = kk & 7;
                    p.w2s[(((size_t)(kt * 8 + nt)) * 64 + l) * 8 + j] = (unsigned short)f2b(p.W2[i2]);
                }
            }
            for (int i = gtid; i <= N; i += gsz) p.deg[i] = 0;   // includes ticket deg[N]
        } break;

        case 1: {
            // ---------------- P1: deg count (atomics) || gemm1 (MFMA) ----------------
            for (int base = gtid * 8; base < E; base += gsz * 8) {
                if (base + 8 <= E) {
                    int4 a = *(const int4*)(p.ei + E + base);
                    int4 b = *(const int4*)(p.ei + E + base + 4);
                    atomicAdd(&p.deg[a.x], 1); atomicAdd(&p.deg[a.y], 1);
                    atomicAdd(&p.deg[a.z], 1); atomicAdd(&p.deg[a.w], 1);
                    atomicAdd(&p.deg[b.x], 1); atomicAdd(&p.deg[b.y], 1);
                    atomicAdd(&p.deg[b.z], 1); atomicAdd(&p.deg[b.w], 1);
                } else {
                    for (int e = base; e < E; ++e) atomicAdd(&p.deg[p.ei[E + e]], 1);
                }
            }
            const int q = lane >> 4, lc = lane & 15;
            const bf16x8* bW = (const bf16x8*)p.w1s;
            for (int t = bid; t < gblk; t += nB) {
                const int m0 = t * 64 + wave * 16;
                const int arow = m0 + lc;
                const float* xrow = p.x + (size_t)min(arow, N - 1) * 512 + q * 8;

                f32x4 acc[4] = {{0.f,0.f,0.f,0.f},{0.f,0.f,0.f,0.f},{0.f,0.f,0.f,0.f},{0.f,0.f,0.f,0.f}};
                for (int kt = 0; kt < 16; ++kt) {
                    float4 a0 = *(const float4*)(xrow + kt * 32);
                    float4 a1 = *(const float4*)(xrow + kt * 32 + 4);
                    bf16x8 af;
                    af[0] = f2b(a0.x); af[1] = f2b(a0.y); af[2] = f2b(a0.z); af[3] = f2b(a0.w);
                    af[4] = f2b(a1.x); af[5] = f2b(a1.y); af[6] = f2b(a1.z); af[7] = f2b(a1.w);
#pragma unroll
                    for (int nt = 0; nt < 4; ++nt) {
                        bf16x8 bf = bW[(size_t)(kt * 4 + nt) * 64 + lane];
                        acc[nt] = __builtin_amdgcn_mfma_f32_16x16x32_bf16(af, bf, acc[nt], 0, 0, 0);
                    }
                }
                float asc[4], adc[4];
#pragma unroll
                for (int nt = 0; nt < 4; ++nt) { asc[nt] = p.as1[nt * 16 + lc]; adc[nt] = p.ad1[nt * 16 + lc]; }
#pragma unroll
                for (int r = 0; r < 4; ++r) {
                    int row = m0 + q * 4 + r;
                    bool ok = row < N;
                    if (ok) {
#pragma unroll
                        for (int nt = 0; nt < 4; ++nt)
                            p.h1b[(size_t)row * 64 + nt * 16 + lc] = (unsigned short)f2b(acc[nt][r]);
                    }
                    float ps[4], pd[4];
#pragma unroll
                    for (int nt = 0; nt < 4; ++nt) { ps[nt] = acc[nt][r] * asc[nt]; pd[nt] = acc[nt][r] * adc[nt]; }
#pragma unroll
                    for (int off = 1; off < 8; off <<= 1) {
#pragma unroll
                        for (int nt = 0; nt < 4; ++nt) {
                            ps[nt] += __shfl_xor(ps[nt], off);
                            pd[nt] += __shfl_xor(pd[nt], off);
                        }
                    }
                    if (ok && !(lc & 7)) {
                        int hb = lc >> 3;
#pragma unroll
                        for (int nt = 0; nt < 4; ++nt) {
                            p.s1[(size_t)row * 8 + nt * 2 + hb] = ps[nt];
                            p.d1[(size_t)row * 8 + nt * 2 + hb] = pd[nt];
                        }
                    }
                }
            }
        } break;

        case 2: {
            // ---------------- P2: offsets (block scan + atomic ticket) ----------------
            for (int c = nB - 1 - bid; c < nb; c += nB) {
                int v[4];
                int idx = c * 1024 + tid * 4;
#pragma unroll
                for (int i = 0; i < 4; ++i) v[i] = (idx + i < N) ? p.deg[idx + i] + 1 : 0;  // +1 self-loop
                int sum = v[0] + v[1] + v[2] + v[3];
                sm[tid] = sum;
                __syncthreads();
                for (int off = 1; off < 256; off <<= 1) {
                    int xv = (tid >= off) ? sm[tid - off] : 0;
                    __syncthreads();
                    sm[tid] += xv;
                    __syncthreads();
                }
                if (tid == 255) chunkBase = atomicAdd(&p.deg[N], sm[255]);
                __syncthreads();
                int run = chunkBase + sm[tid] - sum;
#pragma unroll
                for (int i = 0; i < 4; ++i) {
                    if (idx + i < N) {
                        p.beg[idx + i] = run;
                        p.srcs[run] = idx + i;     // self-loop at slot 0
                        p.wp[idx + i] = run + 1;
                        run += v[i];
                    }
                }
                __syncthreads();
            }
        } break;

        case 3: {
            // ---------------- P3: scatter real edges ----------------
            for (int base = gtid * 4; base < E; base += gsz * 4) {
                if (base + 4 <= E) {
                    int4 s = *(const int4*)(p.ei + base);
                    int4 d = *(const int4*)(p.ei + E + base);
                    int p0 = atomicAdd(&p.wp[d.x], 1);
                    int p1 = atomicAdd(&p.wp[d.y], 1);
                    int p2 = atomicAdd(&p.wp[d.z], 1);
                    int p3 = atomicAdd(&p.wp[d.w], 1);
                    p.srcs[p0] = s.x; p.srcs[p1] = s.y; p.srcs[p2] = s.z; p.srcs[p3] = s.w;
                } else {
                    for (int e = base; e < E; ++e) {
                        int pp = atomicAdd(&p.wp[p.ei[E + e]], 1);
                        p.srcs[pp] = p.ei[e];
                    }
                }
            }
        } break;

        case 4: {
            // ---------------- P4: agg1 (R0-proven structure, 1 node/wave) ----------------
            for (int wid = gw; wid < N; wid += nW) {
                const int b0 = p.beg[wid];
                const int e0 = b0 + p.deg[wid] + 1;
                const int h = lane & 7;
                const int el = lane >> 3;
                const float dvh = p.d1[(size_t)wid * 8 + h];

                float m = -1e30f;
                for (int i = b0 + el; i < e0; i += 8)
                    m = fmaxf(m, leaky(p.s1[(size_t)p.srcs[i] * 8 + h] + dvh));
#pragma unroll
                for (int off = 8; off < 64; off <<= 1)
                    m = fmaxf(m, __shfl_xor(m, off));

                float acc = 0.0f, den = 0.0f;
                for (int base = b0; base < e0; base += 8) {
                    int i = base + el;
                    int src_l = 0; float w_l = 0.0f;
                    if (i < e0) {
                        src_l = p.srcs[i];
                        w_l = __expf(leaky(p.s1[(size_t)src_l * 8 + h] + dvh) - m);
                    }
                    den += w_l;
#pragma unroll
                    for (int j = 0; j < 8; ++j) {
                        float w = __shfl(w_l, j * 8 + (lane >> 3));
                        int src = __builtin_amdgcn_readfirstlane(__shfl(src_l, j * 8));
                        acc += w * bf2f(p.h1b[(size_t)src * 64 + lane]);
                    }
                }
#pragma unroll
                for (int off = 8; off < 64; off <<= 1)
                    den += __shfl_xor(den, off);
                float rden = 1.0f / (__shfl(den, lane >> 3) + 1e-16f);
                p.out1b[(size_t)wid * 64 + lane] = (unsigned short)f2b(elu(acc * rden + p.b1[lane]));
            }
        } break;

        case 5: {
            // ---------------- P5: gemm2 (MFMA, bf16 A) ----------------
            const int q = lane >> 4, lc = lane & 15;
            const bf16x8* bW = (const bf16x8*)p.w2s;
            for (int t = bid; t < gblk; t += nB) {
                const int m0 = t * 64 + wave * 16;
                const int arow = m0 + lc;
                const unsigned short* xrow = p.out1b + (size_t)min(arow, N - 1) * 64 + q * 8;

                f32x4 acc[8] = {{0.f,0.f,0.f,0.f},{0.f,0.f,0.f,0.f},{0.f,0.f,0.f,0.f},{0.f,0.f,0.f,0.f},
                                {0.f,0.f,0.f,0.f},{0.f,0.f,0.f,0.f},{0.f,0.f,0.f,0.f},{0.f,0.f,0.f,0.f}};
#pragma unroll
                for (int kt = 0; kt < 2; ++kt) {
                    bf16x8 af = *(const bf16x8*)(xrow + kt * 32);
#pragma unroll
                    for (int nt = 0; nt < 8; ++nt) {
                        bf16x8 bf = bW[(size_t)(kt * 8 + nt) * 64 + lane];
                        acc[nt] = __builtin_amdgcn_mfma_f32_16x16x32_bf16(af, bf, acc[nt], 0, 0, 0);
                    }
                }
                float asc[8], adc[8];
#pragma unroll
                for (int nt = 0; nt < 8; ++nt) { asc[nt] = p.as2[nt * 16 + lc]; adc[nt] = p.ad2[nt * 16 + lc]; }
#pragma unroll
                for (int r = 0; r < 4; ++r) {
                    int row = m0 + q * 4 + r;
                    bool ok = row < N;
                    if (ok) {
#pragma unroll
                        for (int nt = 0; nt < 8; ++nt)
                            p.h2b[(size_t)row * 128 + nt * 16 + lc] = (unsigned short)f2b(acc[nt][r]);
                    }
                    float ps = 0.f, pd = 0.f;
#pragma unroll
                    for (int nt = 0; nt < 8; ++nt) { ps += acc[nt][r] * asc[nt]; pd += acc[nt][r] * adc[nt]; }
#pragma unroll
                    for (int off = 1; off < 16; off <<= 1) {
                        ps += __shfl_xor(ps, off);
                        pd += __shfl_xor(pd, off);
                    }
                    if (ok && lc == 0) { p.s2[row] = ps; p.d2[row] = pd; }
                }
            }
        } break;

        case 6: {
            // ---------------- P6: agg2 (R0-proven structure, 1 node/wave) ----------------
            for (int wid = gw; wid < N; wid += nW) {
                const int b0 = p.beg[wid];
                const int e0 = b0 + p.deg[wid] + 1;
                const float dv = p.d2[wid];
                const int c0 = lane * 2;

                float m = -1e30f;
                for (int i = b0 + lane; i < e0; i += 64)
                    m = fmaxf(m, leaky(p.s2[p.srcs[i]] + dv));
#pragma unroll
                for (int off = 1; off < 64; off <<= 1)
                    m = fmaxf(m, __shfl_xor(m, off));

                float acc0 = 0.0f, acc1 = 0.0f, den = 0.0f;
                for (int base = b0; base < e0; base += 64) {
                    int i = base + lane;
                    int src_l = 0; float w_l = 0.0f;
                    if (i < e0) {
                        src_l = p.srcs[i];
                        w_l = __expf(leaky(p.s2[src_l] + dv) - m);
                    }
                    den += w_l;
                    const int cnt = min(64, e0 - base);
                    for (int j0 = 0; j0 < cnt; j0 += 8) {
#pragma unroll
                        for (int u = 0; u < 8; ++u) {
                            int j = j0 + u;
                            float w = __shfl(w_l, j);
                            int src = __builtin_amdgcn_readfirstlane(__shfl(src_l, j));
                            unsigned pv = *(const unsigned*)(p.h2b + (size_t)src * 128 + c0);
                            acc0 += w * __uint_as_float(pv << 16);
                            acc1 += w * __uint_as_float(pv & 0xffff0000u);
                        }
                    }
                }
#pragma unroll
                for (int off = 1; off < 64; off <<= 1)
                    den += __shfl_xor(den, off);
                const float rden = 1.0f / (den + 1e-16f);
                float2 o;
                o.x = elu(acc0 * rden + p.b2[c0]);
                o.y = elu(acc1 * rden + p.b2[c0 + 1]);
                *(float2*)(p.out + (size_t)wid * 128 + c0) = o;
            }
        } break;
        }

        if (ph < phi) {            // only executed on the cooperative path
            __threadfence();       // defensive cross-XCD visibility
            grid.sync();
        }
    }
}

extern "C" void kernel_launch(void* const* d_in, const int* in_sizes, int n_in,
                              void* d_out, int out_size, void* d_ws, size_t ws_size,
                              hipStream_t stream) {
    const float* x   = (const float*)d_in[0];
    const int*   ei  = (const int*)d_in[1];
    const float* W1  = (const float*)d_in[2];
    const float* as1 = (const float*)d_in[3];
    const float* ad1 = (const float*)d_in[4];
    const float* b1  = (const float*)d_in[5];
    const float* W2  = (const float*)d_in[6];
    const float* as2 = (const float*)d_in[7];
    const float* ad2 = (const float*)d_in[8];
    const float* b2  = (const float*)d_in[9];

    const int N = in_sizes[0] / 512;
    const int E = in_sizes[1] / 2;

    // ---- workspace layout (no aliasing: deg must survive to P6) ----
    unsigned short* w1s   = (unsigned short*)d_ws;                   // 512*64 bf16
    unsigned short* w2s   = w1s + 512 * 64;                          // 64*128 bf16
    unsigned short* out1b = w2s + 64 * 128;                          // N*64 bf16
    unsigned short* h1b   = out1b + (size_t)N * 64;                  // N*64 bf16
    unsigned short* h2b   = h1b + (size_t)N * 64;                    // N*128 bf16
    float*          s1    = (float*)(h2b + (size_t)N * 128);         // N*8
    float*          d1    = s1 + (size_t)N * 8;                      // N*8
    float*          s2    = d1 + (size_t)N * 8;                      // N
    float*          d2    = s2 + N;                                  // N
    int*            beg   = (int*)(d2 + N);                          // N
    int*            deg   = beg + N;                                 // N+1 (deg[N] = ticket)
    int*            wp    = deg + (N + 1);                           // N
    int*            srcs  = wp + N;                                  // E+N

    GP p;
    p.x = x; p.ei = ei;
    p.W1 = W1; p.as1 = as1; p.ad1 = ad1; p.b1 = b1;
    p.W2 = W2; p.as2 = as2; p.ad2 = ad2; p.b2 = b2;
    p.w1s = w1s; p.w2s = w2s; p.out1b = out1b; p.h1b = h1b; p.h2b = h2b;
    p.s1 = s1; p.d1 = d1; p.s2 = s2; p.d2 = d2;
    p.beg = beg; p.deg = deg; p.wp = wp; p.srcs = srcs;
    p.out = (float*)d_out;
    p.N = N; p.E = E;

    // One-time host-side occupancy query (capture-safe: no stream ops).
    static int coop_blocks = []() -> int {
        int dev = 0;
        if (hipGetDevice(&dev) != hipSuccess) dev = 0;
        hipDeviceProp_t props;
        int cus = 256;
        if (hipGetDeviceProperties(&props, dev) == hipSuccess && props.multiProcessorCount > 0)
            cus = props.multiProcessorCount;
        int maxb = 0;
        if (hipOccupancyMaxActiveBlocksPerMultiprocessor(&maxb, fused_k, 256, 0) != hipSuccess)
            maxb = 0;
        if (maxb <= 0) return 0;               // cooperative path not viable
        long g = (long)cus * maxb;
        if (g > 2048) g = 2048;
        return (int)g;
    }();

    hipError_t err = hipErrorUnknown;
    if (coop_blocks > 0) {
        int lo = 0, hi = 6;
        void* args[] = { &p, &lo, &hi };
        err = hipLaunchCooperativeKernel((const void*)fused_k, dim3(coop_blocks), dim3(256),
                                         args, 0, stream);
    }
    if (err != hipSuccess) {
        (void)hipGetLastError();   // clear sticky error
        // Fallback: 7 sequential launches; kernel boundaries = device barriers.
        for (int ph = 0; ph <= 6; ++ph)
            hipLaunchKernelGGL(fused_k, dim3(1024), dim3(256), 0, stream, p, ph, ph);
    }
}

// Round 4
// 354.885 us; speedup vs baseline: 3.5971x; 3.5971x over previous
//
#include <hip/hip_runtime.h>

#define NEG_SLOPE 0.2f

typedef __attribute__((ext_vector_type(8))) short bf16x8;
typedef __attribute__((ext_vector_type(4))) float f32x4;

__device__ __forceinline__ float leaky(float v) {
    return v > 0.0f ? v : NEG_SLOPE * v;
}
__device__ __forceinline__ float elu(float v) {
    return v > 0.0f ? v : (__expf(v) - 1.0f);
}
__device__ __forceinline__ short f2b(float f) {
    return (short)((__float_as_uint(f) + 0x8000u) >> 16);
}
__device__ __forceinline__ float bf2f(unsigned short v) {
    return __uint_as_float(((unsigned)v) << 16);
}

// ===== prep: zero deg (incl. ticket at deg[N]) + swizzle weights to MFMA B order =====
__global__ void prep_k(const float* __restrict__ W1, const float* __restrict__ W2,
                       unsigned short* __restrict__ w1s, unsigned short* __restrict__ w2s,
                       int* __restrict__ deg, int N) {
    int i = blockIdx.x * 256 + threadIdx.x;
    if (i <= N) deg[i] = 0;                   // includes ticket slot deg[N]
    if (i < 512 * 64) {                       // W1: K=512, Nc=64
        int k = i >> 6, n = i & 63;
        int kt = k >> 5, kk = k & 31;
        int nt = n >> 4, nn = n & 15;
        int lane = (kk >> 3) * 16 + nn, j = kk & 7;
        w1s[(((size_t)(kt * 4 + nt)) * 64 + lane) * 8 + j] = (unsigned short)f2b(W1[i]);
    } else if (i < 512 * 64 + 64 * 128) {     // W2: K=64, Nc=128
        int i2 = i - 512 * 64;
        int k = i2 >> 7, n = i2 & 127;
        int kt = k >> 5, kk = k & 31;
        int nt = n >> 4, nn = n & 15;
        int lane = (kk >> 3) * 16 + nn, j = kk & 7;
        w2s[(((size_t)(kt * 8 + nt)) * 64 + lane) * 8 + j] = (unsigned short)f2b(W2[i2]);
    }
}

// ========== GEMM1 (blocks 0..gblk) || deg count (remaining blocks) ==========
__global__ __launch_bounds__(256) void g1deg_k(const float* __restrict__ X,
                                               const unsigned short* __restrict__ Ws,
                                               const float* __restrict__ Asrc,
                                               const float* __restrict__ Adst,
                                               unsigned short* __restrict__ Hb,
                                               float* __restrict__ S,
                                               float* __restrict__ D,
                                               const int* __restrict__ dst,
                                               int* __restrict__ deg,
                                               int N, int E, int gblk) {
    if ((int)blockIdx.x >= gblk) {
        // ---- degree count over real edges ----
        int wtid = ((int)blockIdx.x - gblk) * 256 + threadIdx.x;
        int base = wtid * 8;
        if (base + 8 <= E) {
            int4 a = *(const int4*)(dst + base);
            int4 b = *(const int4*)(dst + base + 4);
            atomicAdd(&deg[a.x], 1); atomicAdd(&deg[a.y], 1);
            atomicAdd(&deg[a.z], 1); atomicAdd(&deg[a.w], 1);
            atomicAdd(&deg[b.x], 1); atomicAdd(&deg[b.y], 1);
            atomicAdd(&deg[b.z], 1); atomicAdd(&deg[b.w], 1);
        } else {
            for (int e = base; e < E; ++e) atomicAdd(&deg[dst[e]], 1);
        }
        return;
    }
    // ---- gemm1 (R0-proven body) ----
    const int lane = threadIdx.x & 63;
    const int wave = threadIdx.x >> 6;
    const int m0 = blockIdx.x * 64 + wave * 16;
    const int q = lane >> 4, lc = lane & 15;
    const int arow = m0 + lc;
    const float* xrow = X + (size_t)min(arow, N - 1) * 512 + q * 8;
    const bf16x8* bW = (const bf16x8*)Ws;

    f32x4 acc[4] = {{0.f,0.f,0.f,0.f},{0.f,0.f,0.f,0.f},{0.f,0.f,0.f,0.f},{0.f,0.f,0.f,0.f}};

    for (int kt = 0; kt < 16; ++kt) {
        float4 a0 = *(const float4*)(xrow + kt * 32);
        float4 a1 = *(const float4*)(xrow + kt * 32 + 4);
        bf16x8 af;
        af[0] = f2b(a0.x); af[1] = f2b(a0.y); af[2] = f2b(a0.z); af[3] = f2b(a0.w);
        af[4] = f2b(a1.x); af[5] = f2b(a1.y); af[6] = f2b(a1.z); af[7] = f2b(a1.w);
#pragma unroll
        for (int nt = 0; nt < 4; ++nt) {
            bf16x8 bf = bW[(size_t)(kt * 4 + nt) * 64 + lane];
            acc[nt] = __builtin_amdgcn_mfma_f32_16x16x32_bf16(af, bf, acc[nt], 0, 0, 0);
        }
    }

    float asc[4], adc[4];
#pragma unroll
    for (int nt = 0; nt < 4; ++nt) { asc[nt] = Asrc[nt * 16 + lc]; adc[nt] = Adst[nt * 16 + lc]; }

#pragma unroll
    for (int r = 0; r < 4; ++r) {
        int row = m0 + q * 4 + r;
        bool ok = row < N;
        if (ok) {
#pragma unroll
            for (int nt = 0; nt < 4; ++nt)
                Hb[(size_t)row * 64 + nt * 16 + lc] = (unsigned short)f2b(acc[nt][r]);
        }
        float ps[4], pd[4];
#pragma unroll
        for (int nt = 0; nt < 4; ++nt) { ps[nt] = acc[nt][r] * asc[nt]; pd[nt] = acc[nt][r] * adc[nt]; }
#pragma unroll
        for (int off = 1; off < 8; off <<= 1) {
#pragma unroll
            for (int nt = 0; nt < 4; ++nt) {
                ps[nt] += __shfl_xor(ps[nt], off);
                pd[nt] += __shfl_xor(pd[nt], off);
            }
        }
        if (ok && !(lc & 7)) {
            int hb = lc >> 3;
#pragma unroll
            for (int nt = 0; nt < 4; ++nt) {
                S[(size_t)row * 8 + nt * 2 + hb] = ps[nt];
                D[(size_t)row * 8 + nt * 2 + hb] = pd[nt];
            }
        }
    }
}

// ===== offsets: per-chunk block scan + atomic ticket base (R3-verified logic) =====
// Row bases are NOT globally monotonic — aggs use beg[]/deg[] only.
__global__ __launch_bounds__(256) void scan_k(const int* __restrict__ deg_in,
                                              int* __restrict__ ticket,   // = &deg[N]
                                              int* __restrict__ beg,
                                              int* __restrict__ wp,
                                              int* __restrict__ srcs, int N) {
    __shared__ int sm[256];
    __shared__ int chunkBase;
    const int t = threadIdx.x;
    int idx = blockIdx.x * 1024 + t * 4;
    int v[4];
#pragma unroll
    for (int i = 0; i < 4; ++i) v[i] = (idx + i < N) ? deg_in[idx + i] + 1 : 0;  // +1 self-loop
    int sum = v[0] + v[1] + v[2] + v[3];
    sm[t] = sum;
    __syncthreads();
    for (int off = 1; off < 256; off <<= 1) {
        int xv = (t >= off) ? sm[t - off] : 0;
        __syncthreads();
        sm[t] += xv;
        __syncthreads();
    }
    if (t == 255) chunkBase = atomicAdd(ticket, sm[255]);
    __syncthreads();
    int run = chunkBase + sm[t] - sum;
#pragma unroll
    for (int i = 0; i < 4; ++i) {
        if (idx + i < N) {
            beg[idx + i] = run;
            srcs[run] = idx + i;   // self-loop at slot 0
            wp[idx + i] = run + 1;
            run += v[i];
        }
    }
}

// ===== scatter real edges =====
__global__ void scatter_k(const int* __restrict__ ei, int E,
                          int* __restrict__ wp, int* __restrict__ srcs) {
    int base = (blockIdx.x * blockDim.x + threadIdx.x) * 4;
    if (base + 4 <= E) {
        int4 s = *(const int4*)(ei + base);
        int4 d = *(const int4*)(ei + E + base);
        int p0 = atomicAdd(&wp[d.x], 1);
        int p1 = atomicAdd(&wp[d.y], 1);
        int p2 = atomicAdd(&wp[d.z], 1);
        int p3 = atomicAdd(&wp[d.w], 1);
        srcs[p0] = s.x; srcs[p1] = s.y; srcs[p2] = s.z; srcs[p3] = s.w;
    } else {
        for (int e = base; e < E; ++e) {
            int p = atomicAdd(&wp[ei[E + e]], 1);
            srcs[p] = ei[e];
        }
    }
}

// ========= fused agg1 (R0 body, LDS out) + gemm2 tile (16 rows/block) =========
__global__ __launch_bounds__(256) void agg1g2_k(const int* __restrict__ beg,
                                                const int* __restrict__ deg,
                                                const int* __restrict__ srcs,
                                                const float* __restrict__ S1,
                                                const float* __restrict__ D1,
                                                const unsigned short* __restrict__ H1b,
                                                const float* __restrict__ b1,
                                                const unsigned short* __restrict__ W2s,
                                                const float* __restrict__ as2,
                                                const float* __restrict__ ad2,
                                                unsigned short* __restrict__ H2b,
                                                float* __restrict__ S2,
                                                float* __restrict__ D2, int N) {
    __shared__ unsigned short sh[16][64];   // agg1 results (bf16), tile A for gemm2
    __shared__ float shp[4][16], shq[4][16];

    const int tid  = threadIdx.x;
    const int lane = tid & 63;
    const int wave = tid >> 6;
    const int m0 = blockIdx.x * 16;

    // ---------- part A: agg1, 4 nodes per wave (R0-proven body) ----------
    const int h = lane & 7;
    const int el = lane >> 3;
#pragma unroll
    for (int rep = 0; rep < 4; ++rep) {
        const int nl = wave * 4 + rep;          // node-local 0..15
        const int wid = m0 + nl;
        if (wid < N) {
            const int b0 = beg[wid];
            const int e0 = b0 + deg[wid] + 1;
            const float dvh = D1[(size_t)wid * 8 + h];

            float m = -1e30f;
            for (int i = b0 + el; i < e0; i += 8)
                m = fmaxf(m, leaky(S1[(size_t)srcs[i] * 8 + h] + dvh));
#pragma unroll
            for (int off = 8; off < 64; off <<= 1)
                m = fmaxf(m, __shfl_xor(m, off));

            float acc = 0.0f, den = 0.0f;
            for (int base = b0; base < e0; base += 8) {
                int i = base + el;
                int src_l = 0; float w_l = 0.0f;
                if (i < e0) {
                    src_l = srcs[i];
                    w_l = __expf(leaky(S1[(size_t)src_l * 8 + h] + dvh) - m);
                }
                den += w_l;
#pragma unroll
                for (int j = 0; j < 8; ++j) {
                    float w = __shfl(w_l, j * 8 + (lane >> 3));
                    int src = __builtin_amdgcn_readfirstlane(__shfl(src_l, j * 8));
                    acc += w * bf2f(H1b[(size_t)src * 64 + lane]);
                }
            }
#pragma unroll
            for (int off = 8; off < 64; off <<= 1)
                den += __shfl_xor(den, off);
            float rden = 1.0f / (__shfl(den, lane >> 3) + 1e-16f);
            sh[nl][lane] = (unsigned short)f2b(elu(acc * rden + b1[lane]));
        } else {
            sh[nl][lane] = 0;
        }
    }
    __syncthreads();

    // ---------- part B: gemm2 on the 16-row LDS tile; wave owns nt = {2w, 2w+1} ----------
    const int q = lane >> 4, lc = lane & 15;
    const bf16x8* bW = (const bf16x8*)W2s;
    const int nt0 = wave * 2;

    f32x4 acc2[2] = {{0.f,0.f,0.f,0.f},{0.f,0.f,0.f,0.f}};
#pragma unroll
    for (int kt = 0; kt < 2; ++kt) {
        bf16x8 af = *(const bf16x8*)(&sh[lc][q * 8 + kt * 32]);
#pragma unroll
        for (int u = 0; u < 2; ++u) {
            bf16x8 bf = bW[(size_t)(kt * 8 + nt0 + u) * 64 + lane];
            acc2[u] = __builtin_amdgcn_mfma_f32_16x16x32_bf16(af, bf, acc2[u], 0, 0, 0);
        }
    }
    float asc[2], adc[2];
#pragma unroll
    for (int u = 0; u < 2; ++u) {
        asc[u] = as2[(nt0 + u) * 16 + lc];
        adc[u] = ad2[(nt0 + u) * 16 + lc];
    }
#pragma unroll
    for (int r = 0; r < 4; ++r) {
        int rl = q * 4 + r;
        int row = m0 + rl;
        if (row < N) {
#pragma unroll
            for (int u = 0; u < 2; ++u)
                H2b[(size_t)row * 128 + (nt0 + u) * 16 + lc] = (unsigned short)f2b(acc2[u][r]);
        }
        float ps = acc2[0][r] * asc[0] + acc2[1][r] * asc[1];
        float pd = acc2[0][r] * adc[0] + acc2[1][r] * adc[1];
#pragma unroll
        for (int off = 1; off < 16; off <<= 1) {
            ps += __shfl_xor(ps, off);
            pd += __shfl_xor(pd, off);
        }
        if (lc == 0) { shp[wave][rl] = ps; shq[wave][rl] = pd; }
    }
    __syncthreads();
    if (tid < 16) {
        int row = m0 + tid;
        if (row < N) {
            float s = shp[0][tid] + shp[1][tid] + shp[2][tid] + shp[3][tid];
            float d = shq[0][tid] + shq[1][tid] + shq[2][tid] + shq[3][tid];
            S2[row] = s;
            D2[row] = d;
        }
    }
}

// ========= conv2 gather (R0-proven body, beg/deg CSR) =========
__global__ __launch_bounds__(256) void agg2_csr_k(const int* __restrict__ beg,
                                                  const int* __restrict__ deg,
                                                  const int* __restrict__ srcs,
                                                  const float* __restrict__ S,
                                                  const float* __restrict__ D,
                                                  const unsigned short* __restrict__ Hb,
                                                  const float* __restrict__ bias,
                                                  float* __restrict__ out, int N) {
    const int wid = (blockIdx.x * 256 + threadIdx.x) >> 6;
    const int lane = threadIdx.x & 63;
    if (wid >= N) return;
    const int b0 = beg[wid];
    const int e0 = b0 + deg[wid] + 1;
    const float dv = D[wid];
    const int c0 = lane * 2;

    float m = -1e30f;
    for (int i = b0 + lane; i < e0; i += 64)
        m = fmaxf(m, leaky(S[srcs[i]] + dv));
#pragma unroll
    for (int off = 1; off < 64; off <<= 1)
        m = fmaxf(m, __shfl_xor(m, off));

    float acc0 = 0.0f, acc1 = 0.0f, den = 0.0f;
    for (int base = b0; base < e0; base += 64) {
        int i = base + lane;
        int src_l = 0; float w_l = 0.0f;
        if (i < e0) {
            src_l = srcs[i];
            w_l = __expf(leaky(S[src_l] + dv) - m);
        }
        den += w_l;
        const int cnt = min(64, e0 - base);
        for (int j0 = 0; j0 < cnt; j0 += 8) {
#pragma unroll
            for (int u = 0; u < 8; ++u) {
                int j = j0 + u;
                float w = __shfl(w_l, j);
                int src = __builtin_amdgcn_readfirstlane(__shfl(src_l, j));
                unsigned pv = *(const unsigned*)(Hb + (size_t)src * 128 + c0);
                acc0 += w * __uint_as_float(pv << 16);
                acc1 += w * __uint_as_float(pv & 0xffff0000u);
            }
        }
    }
#pragma unroll
    for (int off = 1; off < 64; off <<= 1)
        den += __shfl_xor(den, off);
    const float rden = 1.0f / (den + 1e-16f);
    float2 o;
    o.x = elu(acc0 * rden + bias[c0]);
    o.y = elu(acc1 * rden + bias[c0 + 1]);
    *(float2*)(out + (size_t)wid * 128 + c0) = o;
}

extern "C" void kernel_launch(void* const* d_in, const int* in_sizes, int n_in,
                              void* d_out, int out_size, void* d_ws, size_t ws_size,
                              hipStream_t stream) {
    const float* x   = (const float*)d_in[0];
    const int*   ei  = (const int*)d_in[1];
    const float* W1  = (const float*)d_in[2];
    const float* as1 = (const float*)d_in[3];
    const float* ad1 = (const float*)d_in[4];
    const float* b1  = (const float*)d_in[5];
    const float* W2  = (const float*)d_in[6];
    const float* as2 = (const float*)d_in[7];
    const float* ad2 = (const float*)d_in[8];
    const float* b2  = (const float*)d_in[9];

    const int N = in_sizes[0] / 512;
    const int E = in_sizes[1] / 2;

    // ---- workspace layout (out1b eliminated; deg survives to agg2) ----
    unsigned short* w1s  = (unsigned short*)d_ws;                   // 512*64 bf16
    unsigned short* w2s  = w1s + 512 * 64;                          // 64*128 bf16
    unsigned short* h1b  = w2s + 64 * 128;                          // N*64 bf16
    unsigned short* h2b  = h1b + (size_t)N * 64;                    // N*128 bf16
    float*          s1   = (float*)(h2b + (size_t)N * 128);         // N*8
    float*          d1   = s1 + (size_t)N * 8;                      // N*8
    float*          s2   = d1 + (size_t)N * 8;                      // N
    float*          d2   = s2 + N;                                  // N
    int*            beg  = (int*)(d2 + N);                          // N
    int*            deg  = beg + N;                                 // N+1 (deg[N] = ticket)
    int*            wp   = deg + (N + 1);                           // N
    int*            srcs = wp + N;                                  // E+N

    const int B = 256;
    const int gblk = (N + 63) / 64;                  // gemm1 tiles
    const int degb = (E / 8 + B - 1) / B;            // deg-count blocks (8 edges/thread)
    const int nb   = (N + 1023) / 1024;              // scan chunks
    int prep_n = 512 * 64 + 64 * 128;
    if (N + 1 > prep_n) prep_n = N + 1;

    prep_k<<<(prep_n + B - 1) / B, B, 0, stream>>>(W1, W2, w1s, w2s, deg, N);
    g1deg_k<<<gblk + degb, B, 0, stream>>>(x, w1s, as1, ad1, h1b, s1, d1,
                                           ei + E, deg, N, E, gblk);
    scan_k<<<nb, B, 0, stream>>>(deg, deg + N, beg, wp, srcs, N);
    scatter_k<<<(E + B * 4 - 1) / (B * 4), B, 0, stream>>>(ei, E, wp, srcs);
    agg1g2_k<<<(N + 15) / 16, B, 0, stream>>>(beg, deg, srcs, s1, d1, h1b, b1,
                                              w2s, as2, ad2, h2b, s2, d2, N);
    agg2_csr_k<<<(N + 3) / 4, B, 0, stream>>>(beg, deg, srcs, s2, d2, h2b, b2,
                                              (float*)d_out, N);
}